// Round 5
// baseline (164.513 us; speedup 1.0000x reference)
//
#include <hip/hip_runtime.h>
#include <stdint.h>

#define NPRED 2048
#define MT    512
#define BLK   256
#define NCAND 512
#define REC   2176   // per-batch ws: srt[512]u16 | (unused 1024B) | meta[8]i32

#define M_NPOS  0
#define M_NT    1
#define M_K     2

template<int C>
__device__ __forceinline__ float dppminf(float v) {
  int o = __builtin_amdgcn_update_dpp(__float_as_int(v), __float_as_int(v), C, 0xF, 0xF, false);
  return fminf(v, __int_as_float(o));
}
template<int C>
__device__ __forceinline__ uint32_t dppminu(uint32_t v) {
  uint32_t o = (uint32_t)__builtin_amdgcn_update_dpp((int)v, (int)v, C, 0xF, 0xF, false);
  return v < o ? v : o;
}
__device__ __forceinline__ float wave_min_f32_l63(float v) {
  v = dppminf<0x111>(v); v = dppminf<0x112>(v); v = dppminf<0x114>(v);
  v = dppminf<0x118>(v); v = dppminf<0x142>(v); v = dppminf<0x143>(v);
  return __int_as_float(__builtin_amdgcn_readlane(__float_as_int(v), 63));
}
__device__ __forceinline__ uint32_t wave_min_u32_l63(uint32_t v) {
  v = dppminu<0x111>(v); v = dppminu<0x112>(v); v = dppminu<0x114>(v);
  v = dppminu<0x118>(v); v = dppminu<0x142>(v); v = dppminu<0x143>(v);
  return (uint32_t)__builtin_amdgcn_readlane((int)v, 63);
}

// Exact argmin over 512 targets (8/lane), lowest-index tie-break.
__device__ __forceinline__ int argmin_pred(const float* txr, const float* tyr,
                                           uint32_t okm, float x, float y,
                                           uint32_t lane8) {
  const float INF = __builtin_inff();
  float d[8];
#pragma unroll
  for (int j = 0; j < 8; ++j) {
    float dx = __fsub_rn(txr[j], x);
    float dy = __fsub_rn(tyr[j], y);
    float d2 = __fadd_rn(__fmul_rn(dx, dx), __fmul_rn(dy, dy));
    d[j] = ((okm >> j) & 1u) ? d2 : INF;
  }
  float l1 = fminf(d[0], d[1]), l2 = fminf(d[2], d[3]);
  float l3 = fminf(d[4], d[5]), l4 = fminf(d[6], d[7]);
  float lmin = fminf(fminf(l1, l2), fminf(l3, l4));
  float g = wave_min_f32_l63(lmin);
  int jb = 7;
#pragma unroll
  for (int j = 6; j >= 0; --j) jb = (d[j] == g) ? j : jb;
  uint32_t cnd = (lmin == g) ? (lane8 | (uint32_t)jb) : 0x7FFFFFFFu;
  return (int)wave_min_u32_l63(cnd);
}

// ---- bitonic helpers (static indexing; u32 keys) ----
__device__ __forceinline__ void ce_asc(uint32_t& a, uint32_t& b) {
  uint32_t lo = a < b ? a : b;
  uint32_t hi = a < b ? b : a;
  a = lo; b = hi;
}
__device__ __forceinline__ void ce_desc(uint32_t& a, uint32_t& b) {
  uint32_t lo = a < b ? a : b;
  uint32_t hi = a < b ? b : a;
  a = hi; b = lo;
}
__device__ __forceinline__ void bsort16(uint32_t k[16]) {
#pragma unroll
  for (int kk = 2; kk <= 16; kk <<= 1) {
#pragma unroll
    for (int j = kk >> 1; j > 0; j >>= 1) {
#pragma unroll
      for (int i = 0; i < 16; ++i) {
        int p = i ^ j;
        if (p > i) {
          if ((i & kk) == 0) ce_asc(k[i], k[p]); else ce_desc(k[i], k[p]);
        }
      }
    }
  }
}
__device__ __forceinline__ void bclean16(uint32_t k[16]) {  // bitonic -> asc
#pragma unroll
  for (int j = 8; j > 0; j >>= 1) {
#pragma unroll
    for (int i = 0; i < 16; ++i) {
      int p = i ^ j;
      if (p > i) ce_asc(k[i], k[p]);
    }
  }
}

// ---------------- K1: select + rank-sort + prob loss ----------------
__global__ __launch_bounds__(BLK) void prep_kernel(const float* __restrict__ preds,
                                                   const float* __restrict__ targets,
                                                   uint8_t* __restrict__ recs,
                                                   double* __restrict__ acc) {
  const int b = blockIdx.x;
  const float* __restrict__ P = preds   + (size_t)b * NPRED * 5;
  const float* __restrict__ T = targets + (size_t)b * MT * 5;
  uint16_t* __restrict__ srt = (uint16_t*)(recs + (size_t)b * REC);
  int* __restrict__ meta = (int*)(recs + (size_t)b * REC + 2048);

  __shared__ uint64_t keys[NPRED];
  __shared__ uint64_t cand[NCAND];
  __shared__ int hist[256];
  __shared__ int s_npos, s_nt, s_B, s_ncand;
  __shared__ uint64_t s_thr;
  __shared__ double red[BLK];

  const int tid = threadIdx.x;
  if (tid == 0) { s_npos = 0; s_nt = 0; s_B = 0; s_ncand = 0; s_thr = 0ull; }
  hist[tid] = 0;
  __syncthreads();

  int cpos = 0;
  for (int i = tid; i < NPRED; i += BLK) {
    float c = P[i * 5 + 0];
    cpos += (c > 0.5f) ? 1 : 0;
    uint32_t cb = __float_as_uint(c);
    keys[i] = ((uint64_t)(~cb) << 32) | (uint32_t)i;
    if (cb >= 0x3F000000u && cb < 0x3F800000u)
      atomicAdd(&hist[(cb >> 15) & 0xFF], 1);
  }
  atomicAdd(&s_npos, cpos);

  int ct = 0;
  for (int m = tid; m < MT; m += BLK) ct += (T[m * 5 + 0] == 1.0f) ? 1 : 0;
  atomicAdd(&s_nt, ct);
  __syncthreads();
  const int n_pos = s_npos;
  const int n_targs = s_nt;

  if (tid < 64) {
    const int lane = tid;
    int4 h4 = *reinterpret_cast<const int4*>(&hist[lane * 4]);
    int t = h4.x + h4.y + h4.z + h4.w;
    int S = t;
#pragma unroll
    for (int off = 1; off < 64; off <<= 1) {
      int o = __shfl_down(S, off);
      if (lane + off < 64) S += o;
    }
    int Snext = S - t;
    int s3 = h4.w + Snext;
    int s2 = h4.z + s3;
    int s1 = h4.y + s2;
    int s0 = h4.x + s1;
    int localB = -1;
    if      (s3 >= n_targs) localB = lane * 4 + 3;
    else if (s2 >= n_targs) localB = lane * 4 + 2;
    else if (s1 >= n_targs) localB = lane * 4 + 1;
    else if (s0 >= n_targs) localB = lane * 4 + 0;
    uint64_t q = __ballot(localB >= 0);
    if (q) {
      int hl = 63 - __clzll((long long)q);
      int B = __builtin_amdgcn_readlane(localB, hl);
      if (lane == 0) s_B = B;
    }
  }
  for (int i = tid; i < NCAND; i += BLK) srt[i] = 0;
  __syncthreads();
  const int B = s_B;

  for (int i = tid; i < NPRED; i += BLK) {
    uint64_t k = keys[i];
    uint32_t cb = ~(uint32_t)(k >> 32);
    if (cb >= 0x3F000000u && cb < 0x3F800000u && (int)((cb >> 15) & 0xFF) >= B) {
      int slot = atomicAdd(&s_ncand, 1);
      if (slot < NCAND) cand[slot] = k;
    }
  }
  __syncthreads();
  const int ncand = min(s_ncand, NCAND);

  {
    uint64_t ka = (tid < ncand) ? cand[tid] : ~0ull;
    uint64_t kb = (tid + BLK < ncand) ? cand[tid + BLK] : ~0ull;
    int ra = 0, rb = 0;
    for (int j = 0; j < ncand; ++j) {
      uint64_t kj = cand[j];
      ra += (kj < ka) ? 1 : 0;
      rb += (kj < kb) ? 1 : 0;
    }
    if (tid < ncand) {
      srt[ra] = (uint16_t)(ka & 0xFFFFu);
      if (ra == n_targs - 1) s_thr = ka;
    }
    if (tid + BLK < ncand) {
      srt[rb] = (uint16_t)(kb & 0xFFFFu);
      if (rb == n_targs - 1) s_thr = kb;
    }
  }
  __syncthreads();
  const uint64_t thr = s_thr;

  float accp = 0.f;
  for (int i = tid; i < NPRED; i += BLK) {
    uint64_t k = keys[i];
    float p = __uint_as_float(~(uint32_t)(k >> 32));
    accp += (k <= thr) ? -fmaxf(logf(p), -100.0f)
                       : -fmaxf(log1pf(-p), -100.0f);
  }
  red[tid] = (double)accp;
  __syncthreads();
  for (int s = BLK / 2; s > 0; s >>= 1) {
    if (tid < s) red[tid] += red[tid + s];
    __syncthreads();
  }
  if (tid == 0) {
    atomicAdd(&acc[4], red[0]);
    meta[M_NPOS] = n_pos;
    meta[M_NT]   = n_targs;
    meta[M_K]    = min(n_pos, n_targs);
  }
}

// ---------------- K2: candidate lists + walk match + fused MSE ----------------
__global__ __launch_bounds__(BLK) void match_mse_kernel(const float* __restrict__ preds,
                                                        const float* __restrict__ targets,
                                                        const uint8_t* __restrict__ recs,
                                                        double* __restrict__ acc) {
  const int b = blockIdx.x;
  const int tid = threadIdx.x;
  const float* __restrict__ P = preds   + (size_t)b * NPRED * 5;
  const float* __restrict__ T = targets + (size_t)b * MT * 5;
  const uint16_t* __restrict__ srt = (const uint16_t*)(recs + (size_t)b * REC);
  const int* __restrict__ meta = (const int*)(recs + (size_t)b * REC + 2048);

  __shared__ float txy[MT * 2];          // (tx,ty) interleaved; invalid x poisoned
  __shared__ float tab[MT * 2];          // (ta,tb) interleaved
  __shared__ float spx[512], spy[512], spa[512], spb[512];
  __shared__ uint16_t lists[512 * 16];   // 16 KB candidate lists
  __shared__ uint16_t plds[512];
  __shared__ uint32_t s_valid[16];
  __shared__ int s_first;
  __shared__ double red[4][BLK];

  const int n_pos = meta[M_NPOS], n_targs = meta[M_NT], K = meta[M_K];

  if (tid < 16) s_valid[tid] = 0;
  if (tid == 0) s_first = 0;
  __syncthreads();

  // ---- stage targets (poison invalid x so their d2 is huge) ----
  for (int m = tid; m < MT; m += BLK) {
    float tp = T[m * 5 + 0];
    bool v = (tp == 1.0f);
    txy[2 * m]     = v ? T[m * 5 + 1] : 1e18f;
    txy[2 * m + 1] = T[m * 5 + 2];
    tab[2 * m]     = T[m * 5 + 3];
    tab[2 * m + 1] = T[m * 5 + 4];
    if (v) atomicOr(&s_valid[m >> 5], 1u << (m & 31));
  }
  // ---- stage sorted preds (rows < n_targs; pads zero) ----
  for (int i = tid; i < 512; i += BLK) {
    if (i < n_targs) {
      int pi = srt[i];
      spx[i] = P[pi * 5 + 1];
      spy[i] = P[pi * 5 + 2];
      spa[i] = P[pi * 5 + 3];
      spb[i] = P[pi * 5 + 4];
    } else {
      spx[i] = 0.f; spy[i] = 0.f; spa[i] = 0.f; spb[i] = 0.f;
    }
  }
  __syncthreads();

  // ---- Phase A: per-pred top-16 candidate list (sorted by (d2,idx)) ----
  const float4* t4 = (const float4*)txy;   // 2 targets per float4
  for (int r = tid; r < K; r += BLK) {
    float x = spx[r], y = spy[r];
    uint32_t cur[16];
#pragma unroll
    for (int j = 0; j < 16; ++j) cur[j] = 0xFFFFFFFFu;
    for (int c = 0; c < 32; ++c) {
      uint32_t nk[16];
#pragma unroll
      for (int jj = 0; jj < 8; ++jj) {
        float4 v = t4[c * 8 + jj];
        int t0 = c * 16 + jj * 2;
        float dx0 = __fsub_rn(v.x, x), dy0 = __fsub_rn(v.y, y);
        float d20 = __fadd_rn(__fmul_rn(dx0, dx0), __fmul_rn(dy0, dy0));
        nk[jj * 2] = (__float_as_uint(d20) & 0xFFFFFE00u) | (uint32_t)t0;
        float dx1 = __fsub_rn(v.z, x), dy1 = __fsub_rn(v.w, y);
        float d21 = __fadd_rn(__fmul_rn(dx1, dx1), __fmul_rn(dy1, dy1));
        nk[jj * 2 + 1] = (__float_as_uint(d21) & 0xFFFFFE00u) | (uint32_t)(t0 + 1);
      }
      bsort16(nk);
      // keep lowest 16 of (cur asc) ++ (nk desc): half-cleaner then clean
#pragma unroll
      for (int j = 0; j < 16; ++j) {
        uint32_t o = nk[15 - j];
        cur[j] = cur[j] < o ? cur[j] : o;
      }
      bclean16(cur);
    }
#pragma unroll
    for (int j = 0; j < 16; ++j) lists[r * 16 + j] = (uint16_t)(cur[j] & 0x1FFu);
  }
  __syncthreads();

  // ---- Phase B: serial walk (wave 0) ----
  if (tid < 64) {
    const int lane = tid;
    uint32_t mw[16];
#pragma unroll
    for (int w = 0; w < 16; ++w) mw[w] = s_valid[w];   // 1 = available
    uint32_t okm = (s_valid[lane >> 2] >> ((lane & 3) * 8)) & 0xFFu;
    float txr[8], tyr[8];
#pragma unroll
    for (int j = 0; j < 8; ++j) {
      txr[j] = txy[2 * (lane * 8 + j)];
      tyr[j] = txy[2 * (lane * 8 + j) + 1];
    }

    const int pl = lane & 15;
    uint32_t e0 = lists[0 * 16 + pl];
    uint32_t e1 = lists[(1 & 511) * 16 + pl];
    for (int i = 0; i < K; ++i) {
      uint32_t e2 = lists[(((i + 2) & 511) * 16) + pl];  // prefetch 2 ahead
      uint32_t e = e0;
      uint32_t w = e >> 5;
      uint32_t p0 = (w & 1) ? mw[1]  : mw[0];
      uint32_t p1 = (w & 1) ? mw[3]  : mw[2];
      uint32_t p2 = (w & 1) ? mw[5]  : mw[4];
      uint32_t p3 = (w & 1) ? mw[7]  : mw[6];
      uint32_t p4 = (w & 1) ? mw[9]  : mw[8];
      uint32_t p5 = (w & 1) ? mw[11] : mw[10];
      uint32_t p6 = (w & 1) ? mw[13] : mw[12];
      uint32_t p7 = (w & 1) ? mw[15] : mw[14];
      uint32_t q0 = (w & 2) ? p1 : p0;
      uint32_t q1 = (w & 2) ? p3 : p2;
      uint32_t q2 = (w & 2) ? p5 : p4;
      uint32_t q3 = (w & 2) ? p7 : p6;
      uint32_t r0 = (w & 4) ? q1 : q0;
      uint32_t r1 = (w & 4) ? q3 : q2;
      uint32_t word = (w & 8) ? r1 : r0;
      uint32_t avail = (word >> (e & 31)) & 1u;
      uint64_t bal = __ballot(avail != 0);
      int m_s;
      if (bal != 0) {
        int jf = __ffsll((unsigned long long)bal) - 1;
        m_s = __builtin_amdgcn_readfirstlane(
                __builtin_amdgcn_readlane((int)e, jf));
      } else {
        // exact fallback: wave argmin over remaining valid-unused
        float x = spx[i], y = spy[i];
        m_s = __builtin_amdgcn_readfirstlane(
                argmin_pred(txr, tyr, okm, x, y, (uint32_t)(lane << 3)));
      }
      uint32_t bm = 1u << (m_s & 31);
      switch (m_s >> 5) {
        case 0:  mw[0]  &= ~bm; break;
        case 1:  mw[1]  &= ~bm; break;
        case 2:  mw[2]  &= ~bm; break;
        case 3:  mw[3]  &= ~bm; break;
        case 4:  mw[4]  &= ~bm; break;
        case 5:  mw[5]  &= ~bm; break;
        case 6:  mw[6]  &= ~bm; break;
        case 7:  mw[7]  &= ~bm; break;
        case 8:  mw[8]  &= ~bm; break;
        case 9:  mw[9]  &= ~bm; break;
        case 10: mw[10] &= ~bm; break;
        case 11: mw[11] &= ~bm; break;
        case 12: mw[12] &= ~bm; break;
        case 13: mw[13] &= ~bm; break;
        case 14: mw[14] &= ~bm; break;
        default: mw[15] &= ~bm; break;
      }
      if ((m_s >> 3) == lane) okm &= ~(1u << (m_s & 7));
      if (lane == 0) plds[i] = (uint16_t)m_s;
      e0 = e1; e1 = e2;
    }
    // first valid-unused target (for case_first)
    uint32_t fi = okm ? (uint32_t)(lane * 8 + __ffs(okm) - 1) : 0xFFFFFFFFu;
    fi = wave_min_u32_l63(fi);
    if (lane == 0) s_first = (fi < MT) ? (int)fi : 0;
  }
  __syncthreads();

  // ---- Phase C: fused MSE ----
  float ax = 0.f, ay = 0.f, aa = 0.f, ab = 0.f;
  for (int r = tid; r < K; r += BLK) {
    int m = plds[r];
    float dx = __fsub_rn(spx[r], txy[2 * m]);
    float dy = __fsub_rn(spy[r], txy[2 * m + 1]);
    float da = __fsub_rn(spa[r], tab[2 * m]);
    float db = __fsub_rn(spb[r], tab[2 * m + 1]);
    ax += __fmul_rn(dx, dx);
    ay += __fmul_rn(dy, dy);
    aa += __fmul_rn(da, da);
    ab += __fmul_rn(db, db);
  }
  if (n_pos < n_targs) {
    int f = s_first;
    float fx = txy[2 * f], fy = txy[2 * f + 1];
    float fa = tab[2 * f], fb = tab[2 * f + 1];
    for (int i = n_pos + tid; i < n_targs; i += BLK) {
      float dx = __fsub_rn(spx[i], fx);
      float dy = __fsub_rn(spy[i], fy);
      float da = __fsub_rn(spa[i], fa);
      float db = __fsub_rn(spb[i], fb);
      ax += __fmul_rn(dx, dx);
      ay += __fmul_rn(dy, dy);
      aa += __fmul_rn(da, da);
      ab += __fmul_rn(db, db);
    }
  }
  red[0][tid] = (double)ax;
  red[1][tid] = (double)ay;
  red[2][tid] = (double)aa;
  red[3][tid] = (double)ab;
  __syncthreads();
  for (int s = BLK / 2; s > 0; s >>= 1) {
    if (tid < s) {
#pragma unroll
      for (int c = 0; c < 4; ++c) red[c][tid] += red[c][tid + s];
    }
    __syncthreads();
  }
  if (tid == 0) {
#pragma unroll
    for (int c = 0; c < 4; ++c) atomicAdd(&acc[c], red[c][0]);
  }
}

__global__ void finalize_kernel(const double* __restrict__ acc,
                                float* __restrict__ out, double inv) {
  int c = threadIdx.x;
  if (c < 5) out[c] = (float)(acc[c] * inv);
}

extern "C" void kernel_launch(void* const* d_in, const int* in_sizes, int n_in,
                              void* d_out, int out_size, void* d_ws, size_t ws_size,
                              hipStream_t stream) {
  const float* preds = (const float*)d_in[0];
  const float* targets = (const float*)d_in[1];
  int B = in_sizes[0] / (NPRED * 5);

  double* acc = (double*)d_ws;
  uint8_t* recs = (uint8_t*)d_ws + 64;

  hipMemsetAsync(acc, 0, 5 * sizeof(double), stream);
  prep_kernel<<<B, BLK, 0, stream>>>(preds, targets, recs, acc);
  match_mse_kernel<<<B, BLK, 0, stream>>>(preds, targets, recs, acc);
  finalize_kernel<<<1, 64, 0, stream>>>(acc, (float*)d_out,
                                        1.0 / ((double)B * NPRED));
}